// Round 4
// baseline (1541.248 us; speedup 1.0000x reference)
//
#include <hip/hip_runtime.h>
#include <math.h>
#include <stdint.h>

#define B 2
#define N 10000
#define H 8
#define HC 32
#define UV 25
#define DD 5
#define HW 400        // N / UV
#define L 50000       // DD * N
#define UVHW 10000    // UV * HW
#define MCOL 125      // UV * DD
#define HHC 256       // H*HC floats per qkv row
#define HPAD 36       // per-head stride in padded LDS row (36*4B=144B: 16B-aligned, !=0 mod 32 banks)
#define KROW 292      // 8*HPAD + 4 pad; 292*4=1168B (16B-aligned row stride)
#define PROW 201      // aw7 padded row (odd -> stride 9 mod 32, scalar access)
#define P3ROW 200     // bf16 elems per p3 row (h*25+v)

static __device__ __forceinline__ float bf2f(unsigned short u) {
    unsigned int x = ((unsigned int)u) << 16;
    return __builtin_bit_cast(float, x);
}
static __device__ __forceinline__ unsigned short f2bf(float f) {
    unsigned int x = __builtin_bit_cast(unsigned int, f);
    x += 0x7fffu + ((x >> 16) & 1u);
    return (unsigned short)(x >> 16);
}

// ---------------- Kernel 0: invert attn_idx2 permutation ----------------
__global__ __launch_bounds__(256) void k_inv(const int* __restrict__ attn_idx2,
                                             int* __restrict__ inv2) {
    int i = blockIdx.x * 256 + threadIdx.x;
    if (i < L) inv2[attn_idx2[i]] = i;
}

// ---- Kernel 1: grouped QK^T, all heads per block, q in regs, k broadcast from LDS ----
__global__ __launch_bounds__(256) void k_qk(const float* __restrict__ qkv,
                                            const int* __restrict__ attn_idx,
                                            float* __restrict__ aw2) {
    const float SCALE = 0.17677669529663687f; // 1/sqrt(32)
    int bid = blockIdx.x;               // over B*DD*HW = 4000
    int b = bid / (DD * HW);
    int rem = bid % (DD * HW);
    int d = rem / HW, w = rem % HW;
    int t = threadIdx.x;

    __shared__ int idx[UV];
    __shared__ __align__(16) float ks[UV][KROW];

    if (t < UV) idx[t] = attn_idx[(d * UV + t) * HW + w];
    __syncthreads();

    // stage K rows (1 KB = all 8 heads) coalesced into per-head-padded LDS
    for (int e = t; e < UV * 64; e += 256) {
        int u = e >> 6, c4 = e & 63;
        const float4* src = (const float4*)(qkv + ((size_t)(B + b) * N + idx[u]) * HHC) + c4;
        float4 val = *src;
        *(float4*)&ks[u][(c4 >> 3) * HPAD + (c4 & 7) * 4] = val;
    }

    // this thread's q row chunk (one head) straight to registers
    int h = t / UV, u = t % UV;         // valid for t < 200
    float4 q4[8];
    if (t < H * UV) {
        const float4* qsrc = (const float4*)(qkv + ((size_t)b * N + idx[u]) * HHC) + h * 8;
#pragma unroll
        for (int c4 = 0; c4 < 8; ++c4) q4[c4] = qsrc[c4];
    }
    __syncthreads();

    if (t < H * UV) {
        float acc[UV];
#pragma unroll
        for (int v = 0; v < UV; ++v) acc[v] = 0.f;
#pragma unroll
        for (int c4 = 0; c4 < 8; ++c4) {
            float4 q = q4[c4];
#pragma unroll
            for (int v = 0; v < UV; ++v) {   // k read broadcast across the 25 u-lanes
                float4 k = *(const float4*)&ks[v][h * HPAD + c4 * 4];
                acc[v] += q.x * k.x + q.y * k.y + q.z * k.z + q.w * k.w;
            }
        }
        int lu = (d * UV + u) * HW + w;
        float* dst = aw2 + ((size_t)((size_t)b * L + lu) * H + h) * UV;
#pragma unroll
        for (int v = 0; v < UV; ++v) dst[v] = acc[v] * SCALE;
    }
}

// ------- Kernel 2: gather(attn_inv) + mask + softmax + disp; scatter p3(bf16)[b][m][h*25+v] -------
__global__ __launch_bounds__(256) void k_softmax(const float* __restrict__ aw2,
                                                 const int* __restrict__ attn_inv,
                                                 const int* __restrict__ inv2,
                                                 const void* __restrict__ maskbuf,
                                                 const float* __restrict__ disp_map,
                                                 unsigned short* __restrict__ p3,
                                                 float* __restrict__ disp) {
    int bid = blockIdx.x;               // over B*UVHW = 20000
    int b = bid / UVHW, j = bid % UVHW;
    int t = threadIdx.x;
    int h = t >> 5, lane = t & 31;      // 8 half-waves of 32 lanes, one head each

    __shared__ int linv[DD];
    __shared__ int minv2[DD];
    __shared__ int s_flag;
    __shared__ float sp[DD][H][UV];     // staged p for coalesced scatter

    if (t == 0) s_flag = 0;
    if (t < DD) {
        linv[t] = attn_inv[t * UVHW + j];
        minv2[t] = inv2[t * UVHW + j];
    }
    __syncthreads();
    // detect mask encoding: int32 (widened) has all bytes at offset%4!=0 == 0
    const unsigned char* mb = (const unsigned char*)maskbuf;
    if (t < 64) {
        if (mb[4 * t + 1] | mb[4 * t + 2] | mb[4 * t + 3]) s_flag = 1;
    }
    __syncthreads();
    bool isbyte = (s_flag != 0);
    const int* mw = (const int*)maskbuf;

    float vals[4];
    float m = -INFINITY;
#pragma unroll
    for (int kk = 0; kk < 4; ++kk) {
        int e = lane + kk * 32;
        float x = -INFINITY;
        if (e < MCOL) {
            int v = e / DD, d2 = e % DD;
            int l = linv[d2];
            float raw = aw2[((size_t)((size_t)b * L + l) * H + h) * UV + v];
            int mv = isbyte ? (int)mb[(size_t)j * MCOL + e] : mw[(size_t)j * MCOL + e];
            x = mv ? raw : -INFINITY;
        }
        vals[kk] = x;
        m = fmaxf(m, x);
    }
#pragma unroll
    for (int s = 16; s >= 1; s >>= 1) m = fmaxf(m, __shfl_xor(m, s, 32));
    float sum = 0.f;
#pragma unroll
    for (int kk = 0; kk < 4; ++kk) {
        float pe = expf(vals[kk] - m);  // -inf -> 0
        vals[kk] = pe;
        sum += pe;
    }
#pragma unroll
    for (int s = 16; s >= 1; s >>= 1) sum += __shfl_xor(sum, s, 32);
    float inv = 1.0f / sum;
    float dacc = 0.f;
#pragma unroll
    for (int kk = 0; kk < 4; ++kk) {
        int e = lane + kk * 32;
        if (e < MCOL) {
            float pe = vals[kk] * inv;
            int v = e / DD, d2 = e % DD;
            sp[d2][h][v] = pe;
            dacc += pe * disp_map[e];
        }
    }
#pragma unroll
    for (int s = 16; s >= 1; s >>= 1) dacc += __shfl_xor(dacc, s, 32);
    if (lane == 0) disp[((size_t)b * UVHW + j) * H + h] = dacc;
    __syncthreads();
    // scatter: 5 chunks of 400 contiguous bytes (one per d2 -> row m), bf16
    for (int e2 = t; e2 < DD * H * UV; e2 += 256) {
        int d2 = e2 / (H * UV);
        int r = e2 % (H * UV);          // = h*25 + v
        p3[((size_t)b * L + minv2[d2]) * P3ROW + r] = f2bf(sp[d2][r / UV][r % UV]);
    }
}

// ---- Kernel 3: PV, all heads per block, p+V staged once, broadcast V, reg acc, atomics ----
__global__ __launch_bounds__(256) void k_pv(const float* __restrict__ qkv,
                                            const int* __restrict__ attn_idx,
                                            const unsigned short* __restrict__ p3,
                                            float* __restrict__ attn_out) {
    int bid = blockIdx.x;               // over B*DD*HW = 4000
    int b = bid / (DD * HW);
    int rem = bid % (DD * HW);
    int d = rem / HW, w = rem % HW;
    int t = threadIdx.x;

    __shared__ int idxv[UV];
    __shared__ __align__(16) float vs[UV][KROW];
    __shared__ float aw7[UV][PROW];

    if (t < UV) idxv[t] = attn_idx[(d * UV + t) * HW + w];
    __syncthreads();

    for (int e = t; e < UV * 64; e += 256) {
        int v = e >> 6, c4 = e & 63;
        const float4* src = (const float4*)(qkv + ((size_t)(2 * B + b) * N + idxv[v]) * HHC) + c4;
        float4 val = *src;
        *(float4*)&vs[v][(c4 >> 3) * HPAD + (c4 & 7) * 4] = val;
    }
    // p3 rows: m = (d*25+u)*400+w, 400 B (200 bf16) contiguous -> aw7[u][h*25+v] as float
    for (int e = t; e < UV * 25; e += 256) {
        int u = e / 25, jj = e % 25;
        int m = (d * UV + u) * HW + w;
        uint4 pk = *((const uint4*)(p3 + ((size_t)b * L + m) * P3ROW) + jj);
        float* dst = &aw7[u][jj * 8];
        unsigned int wd[4] = {pk.x, pk.y, pk.z, pk.w};
#pragma unroll
        for (int q = 0; q < 4; ++q) {
            dst[q * 2 + 0] = bf2f((unsigned short)(wd[q] & 0xffffu));
            dst[q * 2 + 1] = bf2f((unsigned short)(wd[q] >> 16));
        }
    }
    __syncthreads();

    if (t < H * UV) {
        int h = t / UV, u = t % UV;
        float4 acc4[8];
#pragma unroll
        for (int c4 = 0; c4 < 8; ++c4) acc4[c4] = make_float4(0.f, 0.f, 0.f, 0.f);
        const float* arow = &aw7[u][h * UV];
#pragma unroll
        for (int v = 0; v < UV; ++v) {
            float a = arow[v];
#pragma unroll
            for (int c4 = 0; c4 < 8; ++c4) {  // vs read broadcast across the 25 u-lanes
                float4 vv = *(const float4*)&vs[v][h * HPAD + c4 * 4];
                acc4[c4].x += a * vv.x; acc4[c4].y += a * vv.y;
                acc4[c4].z += a * vv.z; acc4[c4].w += a * vv.w;
            }
        }
        float* obase = attn_out + ((size_t)((size_t)b * N + idxv[u]) * H + h) * HC;
#pragma unroll
        for (int c4 = 0; c4 < 8; ++c4) {
            atomicAdd(obase + c4 * 4 + 0, acc4[c4].x);
            atomicAdd(obase + c4 * 4 + 1, acc4[c4].y);
            atomicAdd(obase + c4 * 4 + 2, acc4[c4].z);
            atomicAdd(obase + c4 * 4 + 3, acc4[c4].w);
        }
    }
}

extern "C" void kernel_launch(void* const* d_in, const int* in_sizes, int n_in,
                              void* d_out, int out_size, void* d_ws, size_t ws_size,
                              hipStream_t stream) {
    const float* qkv      = (const float*)d_in[0];
    const float* disp_map = (const float*)d_in[1];
    const void*  mask     = d_in[2];
    const int*   attn_idx  = (const int*)d_in[3];
    const int*   attn_idx2 = (const int*)d_in[4];
    const int*   attn_inv  = (const int*)d_in[5];

    float* attn_out = (float*)d_out;                          // B*N*H*HC
    float* disp     = (float*)d_out + (size_t)B * N * H * HC; // B*UVHW*H

    float* aw2 = (float*)d_ws;                                     // B*L*H*UV floats (80 MB)
    unsigned short* p3 = (unsigned short*)(aw2 + (size_t)B * L * H * UV); // B*L*200 bf16 (40 MB)
    int* inv2 = (int*)(p3 + (size_t)B * L * P3ROW);                // L ints (0.2 MB)

    // attn_out is accumulated via atomics -> must be zeroed every call
    hipMemsetAsync(d_out, 0, (size_t)B * N * H * HC * sizeof(float), stream);

    k_inv<<<(L + 255) / 256, 256, 0, stream>>>(attn_idx2, inv2);
    k_qk<<<B * DD * HW, 256, 0, stream>>>(qkv, attn_idx, aw2);
    k_softmax<<<B * UVHW, 256, 0, stream>>>(aw2, attn_inv, inv2, mask, disp_map, p3, disp);
    k_pv<<<B * DD * HW * H / H, 256, 0, stream>>>(qkv, attn_idx, p3, attn_out);
}

// Round 5
// 275.109 us; speedup vs baseline: 5.6023x; 5.6023x over previous
//
#include <hip/hip_runtime.h>
#include <math.h>
#include <stdint.h>

#define B 2
#define N 10000
#define H 8
#define HC 32
#define UV 25
#define DD 5
#define HW 400        // N / UV
#define L 50000       // DD * N
#define UVHW 10000    // UV * HW
#define MCOL 125      // UV * DD
#define HHC 256       // H*HC floats per qkv row
#define HPAD 36       // per-head stride in padded LDS row (36*4B=144B: 16B-aligned, !=0 mod 32 banks)
#define KROW 292      // 8*HPAD + 4 pad; 292*4=1168B (16B-aligned row stride)
#define PROW 201      // aw7 padded row (odd -> stride 9 mod 32, scalar access)
#define P3ROW 200     // bf16 elems per p3 row (h*25+v)

static __device__ __forceinline__ float bf2f(unsigned short u) {
    unsigned int x = ((unsigned int)u) << 16;
    return __builtin_bit_cast(float, x);
}
static __device__ __forceinline__ unsigned short f2bf(float f) {
    unsigned int x = __builtin_bit_cast(unsigned int, f);
    x += 0x7fffu + ((x >> 16) & 1u);
    return (unsigned short)(x >> 16);
}

// ---------------- Kernel 0: invert attn_idx2 permutation ----------------
__global__ __launch_bounds__(256) void k_inv(const int* __restrict__ attn_idx2,
                                             int* __restrict__ inv2) {
    int i = blockIdx.x * 256 + threadIdx.x;
    if (i < L) inv2[attn_idx2[i]] = i;
}

// ---- Kernel 1: grouped QK^T, all heads per block, q in regs, k broadcast from LDS ----
__global__ __launch_bounds__(256) void k_qk(const float* __restrict__ qkv,
                                            const int* __restrict__ attn_idx,
                                            float* __restrict__ aw2) {
    const float SCALE = 0.17677669529663687f; // 1/sqrt(32)
    int bid = blockIdx.x;               // over B*DD*HW = 4000
    int b = bid / (DD * HW);
    int rem = bid % (DD * HW);
    int d = rem / HW, w = rem % HW;
    int t = threadIdx.x;

    __shared__ int idx[UV];
    __shared__ __align__(16) float ks[UV][KROW];

    if (t < UV) idx[t] = attn_idx[(d * UV + t) * HW + w];
    __syncthreads();

    // stage K rows (1 KB = all 8 heads) coalesced into per-head-padded LDS
    for (int e = t; e < UV * 64; e += 256) {
        int u = e >> 6, c4 = e & 63;
        const float4* src = (const float4*)(qkv + ((size_t)(B + b) * N + idx[u]) * HHC) + c4;
        float4 val = *src;
        *(float4*)&ks[u][(c4 >> 3) * HPAD + (c4 & 7) * 4] = val;
    }

    // this thread's q row chunk (one head) straight to registers
    int h = t / UV, u = t % UV;         // valid for t < 200
    float4 q4[8];
    if (t < H * UV) {
        const float4* qsrc = (const float4*)(qkv + ((size_t)b * N + idx[u]) * HHC) + h * 8;
#pragma unroll
        for (int c4 = 0; c4 < 8; ++c4) q4[c4] = qsrc[c4];
    }
    __syncthreads();

    if (t < H * UV) {
        float acc[UV];
#pragma unroll
        for (int v = 0; v < UV; ++v) acc[v] = 0.f;
#pragma unroll
        for (int c4 = 0; c4 < 8; ++c4) {
            float4 q = q4[c4];
#pragma unroll
            for (int v = 0; v < UV; ++v) {   // k read broadcast across the 25 u-lanes
                float4 k = *(const float4*)&ks[v][h * HPAD + c4 * 4];
                acc[v] += q.x * k.x + q.y * k.y + q.z * k.z + q.w * k.w;
            }
        }
        int lu = (d * UV + u) * HW + w;
        float* dst = aw2 + ((size_t)((size_t)b * L + lu) * H + h) * UV;
#pragma unroll
        for (int v = 0; v < UV; ++v) dst[v] = acc[v] * SCALE;
    }
}

// ------- Kernel 2: gather(attn_inv) + mask + softmax + disp; scatter p3(bf16)[b][m][h*25+v] -------
__global__ __launch_bounds__(256) void k_softmax(const float* __restrict__ aw2,
                                                 const int* __restrict__ attn_inv,
                                                 const int* __restrict__ inv2,
                                                 const void* __restrict__ maskbuf,
                                                 const float* __restrict__ disp_map,
                                                 unsigned short* __restrict__ p3,
                                                 float* __restrict__ disp) {
    int bid = blockIdx.x;               // over B*UVHW = 20000
    int b = bid / UVHW, j = bid % UVHW;
    int t = threadIdx.x;
    int h = t >> 5, lane = t & 31;      // 8 half-waves of 32 lanes, one head each

    __shared__ int linv[DD];
    __shared__ int minv2[DD];
    __shared__ int s_flag;
    __shared__ float sp[DD][H][UV];     // staged p for coalesced scatter

    if (t == 0) s_flag = 0;
    if (t < DD) {
        linv[t] = attn_inv[t * UVHW + j];
        minv2[t] = inv2[t * UVHW + j];
    }
    __syncthreads();
    // detect mask encoding: int32 (widened) has all bytes at offset%4!=0 == 0
    const unsigned char* mb = (const unsigned char*)maskbuf;
    if (t < 64) {
        if (mb[4 * t + 1] | mb[4 * t + 2] | mb[4 * t + 3]) s_flag = 1;
    }
    __syncthreads();
    bool isbyte = (s_flag != 0);
    const int* mw = (const int*)maskbuf;

    float vals[4];
    float m = -INFINITY;
#pragma unroll
    for (int kk = 0; kk < 4; ++kk) {
        int e = lane + kk * 32;
        float x = -INFINITY;
        if (e < MCOL) {
            int v = e / DD, d2 = e % DD;
            int l = linv[d2];
            float raw = aw2[((size_t)((size_t)b * L + l) * H + h) * UV + v];
            int mv = isbyte ? (int)mb[(size_t)j * MCOL + e] : mw[(size_t)j * MCOL + e];
            x = mv ? raw : -INFINITY;
        }
        vals[kk] = x;
        m = fmaxf(m, x);
    }
#pragma unroll
    for (int s = 16; s >= 1; s >>= 1) m = fmaxf(m, __shfl_xor(m, s, 32));
    float sum = 0.f;
#pragma unroll
    for (int kk = 0; kk < 4; ++kk) {
        float pe = expf(vals[kk] - m);  // -inf -> 0
        vals[kk] = pe;
        sum += pe;
    }
#pragma unroll
    for (int s = 16; s >= 1; s >>= 1) sum += __shfl_xor(sum, s, 32);
    float inv = 1.0f / sum;
    float dacc = 0.f;
#pragma unroll
    for (int kk = 0; kk < 4; ++kk) {
        int e = lane + kk * 32;
        if (e < MCOL) {
            float pe = vals[kk] * inv;
            int v = e / DD, d2 = e % DD;
            sp[d2][h][v] = pe;
            dacc += pe * disp_map[e];
        }
    }
#pragma unroll
    for (int s = 16; s >= 1; s >>= 1) dacc += __shfl_xor(dacc, s, 32);
    if (lane == 0) disp[((size_t)b * UVHW + j) * H + h] = dacc;
    __syncthreads();
    // scatter: 5 chunks of 400 contiguous bytes (one per d2 -> row m), bf16
    for (int e2 = t; e2 < DD * H * UV; e2 += 256) {
        int d2 = e2 / (H * UV);
        int r = e2 % (H * UV);          // = h*25 + v
        p3[((size_t)b * L + minv2[d2]) * P3ROW + r] = f2bf(sp[d2][r / UV][r % UV]);
    }
}

// ---- Kernel 3: PV, all heads per block, p+V staged once, broadcast V, reg acc,
//      epilogue: LDS-staged transpose -> wave-coalesced atomics ----
__global__ __launch_bounds__(256) void k_pv(const float* __restrict__ qkv,
                                            const int* __restrict__ attn_idx,
                                            const unsigned short* __restrict__ p3,
                                            float* __restrict__ attn_out) {
    int bid = blockIdx.x;               // over B*DD*HW = 4000
    int b = bid / (DD * HW);
    int rem = bid % (DD * HW);
    int d = rem / HW, w = rem % HW;
    int t = threadIdx.x;

    __shared__ int idxv[UV];
    __shared__ union {
        struct {
            float vs[UV][KROW];         // 29.2 KB
            float aw7[UV][PROW];        // 20.1 KB
        } c;
        float sacc[H * UV][HC + 1];     // 26.4 KB (reused after compute)
    } smem;

    if (t < UV) idxv[t] = attn_idx[(d * UV + t) * HW + w];
    __syncthreads();

    for (int e = t; e < UV * 64; e += 256) {
        int v = e >> 6, c4 = e & 63;
        const float4* src = (const float4*)(qkv + ((size_t)(2 * B + b) * N + idxv[v]) * HHC) + c4;
        float4 val = *src;
        *(float4*)&smem.c.vs[v][(c4 >> 3) * HPAD + (c4 & 7) * 4] = val;
    }
    // p3 rows: m = (d*25+u)*400+w, 400 B (200 bf16) contiguous -> aw7[u][h*25+v] as float
    for (int e = t; e < UV * 25; e += 256) {
        int u = e / 25, jj = e % 25;
        int m = (d * UV + u) * HW + w;
        uint4 pk = *((const uint4*)(p3 + ((size_t)b * L + m) * P3ROW) + jj);
        float* dst = &smem.c.aw7[u][jj * 8];
        unsigned int wd[4] = {pk.x, pk.y, pk.z, pk.w};
#pragma unroll
        for (int q = 0; q < 4; ++q) {
            dst[q * 2 + 0] = bf2f((unsigned short)(wd[q] & 0xffffu));
            dst[q * 2 + 1] = bf2f((unsigned short)(wd[q] >> 16));
        }
    }
    __syncthreads();

    int h = t / UV, u = t % UV;         // valid for t < 200
    float4 acc4[8];
    if (t < H * UV) {
#pragma unroll
        for (int c4 = 0; c4 < 8; ++c4) acc4[c4] = make_float4(0.f, 0.f, 0.f, 0.f);
        const float* arow = &smem.c.aw7[u][h * UV];
#pragma unroll
        for (int v = 0; v < UV; ++v) {
            float a = arow[v];
#pragma unroll
            for (int c4 = 0; c4 < 8; ++c4) {  // vs read broadcast across the 25 u-lanes
                float4 vv = *(const float4*)&smem.c.vs[v][h * HPAD + c4 * 4];
                acc4[c4].x += a * vv.x; acc4[c4].y += a * vv.y;
                acc4[c4].z += a * vv.z; acc4[c4].w += a * vv.w;
            }
        }
    }
    __syncthreads();                    // done reading vs/aw7; LDS reused below

    if (t < H * UV) {
#pragma unroll
        for (int c4 = 0; c4 < 8; ++c4) {
            smem.sacc[t][c4 * 4 + 0] = acc4[c4].x;
            smem.sacc[t][c4 * 4 + 1] = acc4[c4].y;
            smem.sacc[t][c4 * 4 + 2] = acc4[c4].z;
            smem.sacc[t][c4 * 4 + 3] = acc4[c4].w;
        }
    }
    __syncthreads();

    // wave-coalesced atomics: e = u*256 + h*32 + c -> 64 consecutive floats per wave
    for (int e = t; e < UV * H * HC; e += 256) {
        int uo = e >> 8, r = e & 255;   // r = h*32 + c
        float val = smem.sacc[(r >> 5) * UV + uo][r & 31];
        atomicAdd(attn_out + ((size_t)b * N + idxv[uo]) * HHC + r, val);
    }
}

extern "C" void kernel_launch(void* const* d_in, const int* in_sizes, int n_in,
                              void* d_out, int out_size, void* d_ws, size_t ws_size,
                              hipStream_t stream) {
    const float* qkv      = (const float*)d_in[0];
    const float* disp_map = (const float*)d_in[1];
    const void*  mask     = d_in[2];
    const int*   attn_idx  = (const int*)d_in[3];
    const int*   attn_idx2 = (const int*)d_in[4];
    const int*   attn_inv  = (const int*)d_in[5];

    float* attn_out = (float*)d_out;                          // B*N*H*HC
    float* disp     = (float*)d_out + (size_t)B * N * H * HC; // B*UVHW*H

    float* aw2 = (float*)d_ws;                                     // B*L*H*UV floats (80 MB)
    unsigned short* p3 = (unsigned short*)(aw2 + (size_t)B * L * H * UV); // B*L*200 bf16 (40 MB)
    int* inv2 = (int*)(p3 + (size_t)B * L * P3ROW);                // L ints (0.2 MB)

    // attn_out is accumulated via atomics -> must be zeroed every call
    hipMemsetAsync(d_out, 0, (size_t)B * N * H * HC * sizeof(float), stream);

    k_inv<<<(L + 255) / 256, 256, 0, stream>>>(attn_idx2, inv2);
    k_qk<<<B * DD * HW, 256, 0, stream>>>(qkv, attn_idx, aw2);
    k_softmax<<<B * UVHW, 256, 0, stream>>>(aw2, attn_inv, inv2, mask, disp_map, p3, disp);
    k_pv<<<B * DD * HW, 256, 0, stream>>>(qkv, attn_idx, p3, attn_out);
}

// Round 6
// 217.135 us; speedup vs baseline: 7.0981x; 1.2670x over previous
//
#include <hip/hip_runtime.h>
#include <math.h>
#include <stdint.h>

#define B 2
#define N 10000
#define H 8
#define HC 32
#define UV 25
#define DD 5
#define HW 400        // N / UV
#define L 50000       // DD * N
#define UVHW 10000    // UV * HW
#define MCOL 125      // UV * DD
#define HHC 256       // H*HC floats per qkv row
#define HPAD 36       // per-head stride in padded LDS row (k_qk)
#define KROW 292      // 8*HPAD + 4 pad (k_qk)
#define P3ROW 256     // bf16 elems per p3 row: h*32 + v (64B-aligned head slices)

static __device__ __forceinline__ float bf2f(unsigned short u) {
    unsigned int x = ((unsigned int)u) << 16;
    return __builtin_bit_cast(float, x);
}
static __device__ __forceinline__ unsigned short f2bf(float f) {
    unsigned int x = __builtin_bit_cast(unsigned int, f);
    x += 0x7fffu + ((x >> 16) & 1u);
    return (unsigned short)(x >> 16);
}

// ---------------- Kernel 0: invert attn_idx2 permutation ----------------
__global__ __launch_bounds__(256) void k_inv(const int* __restrict__ attn_idx2,
                                             int* __restrict__ inv2) {
    int i = blockIdx.x * 256 + threadIdx.x;
    if (i < L) inv2[attn_idx2[i]] = i;
}

// ---- Kernel 1: grouped QK^T, all heads per block, q in regs, k broadcast from LDS ----
__global__ __launch_bounds__(256) void k_qk(const float* __restrict__ qkv,
                                            const int* __restrict__ attn_idx,
                                            float* __restrict__ aw2) {
    const float SCALE = 0.17677669529663687f; // 1/sqrt(32)
    int bid = blockIdx.x;               // over B*DD*HW = 4000
    int b = bid / (DD * HW);
    int rem = bid % (DD * HW);
    int d = rem / HW, w = rem % HW;
    int t = threadIdx.x;

    __shared__ int idx[UV];
    __shared__ __align__(16) float ks[UV][KROW];

    if (t < UV) idx[t] = attn_idx[(d * UV + t) * HW + w];
    __syncthreads();

    // stage K rows (1 KB = all 8 heads) coalesced into per-head-padded LDS
    for (int e = t; e < UV * 64; e += 256) {
        int u = e >> 6, c4 = e & 63;
        const float4* src = (const float4*)(qkv + ((size_t)(B + b) * N + idx[u]) * HHC) + c4;
        float4 val = *src;
        *(float4*)&ks[u][(c4 >> 3) * HPAD + (c4 & 7) * 4] = val;
    }

    // this thread's q row chunk (one head) straight to registers
    int h = t / UV, u = t % UV;         // valid for t < 200
    float4 q4[8];
    if (t < H * UV) {
        const float4* qsrc = (const float4*)(qkv + ((size_t)b * N + idx[u]) * HHC) + h * 8;
#pragma unroll
        for (int c4 = 0; c4 < 8; ++c4) q4[c4] = qsrc[c4];
    }
    __syncthreads();

    if (t < H * UV) {
        float acc[UV];
#pragma unroll
        for (int v = 0; v < UV; ++v) acc[v] = 0.f;
#pragma unroll
        for (int c4 = 0; c4 < 8; ++c4) {
            float4 q = q4[c4];
#pragma unroll
            for (int v = 0; v < UV; ++v) {   // k read broadcast across the 25 u-lanes
                float4 k = *(const float4*)&ks[v][h * HPAD + c4 * 4];
                acc[v] += q.x * k.x + q.y * k.y + q.z * k.z + q.w * k.w;
            }
        }
        int lu = (d * UV + u) * HW + w;
        float* dst = aw2 + ((size_t)((size_t)b * L + lu) * H + h) * UV;
#pragma unroll
        for (int v = 0; v < UV; ++v) dst[v] = acc[v] * SCALE;
    }
}

// ------- Kernel 2: gather(attn_inv) + mask + softmax + disp; scatter p3(bf16)[b][m][h*32+v] -------
__global__ __launch_bounds__(256) void k_softmax(const float* __restrict__ aw2,
                                                 const int* __restrict__ attn_inv,
                                                 const int* __restrict__ inv2,
                                                 const void* __restrict__ maskbuf,
                                                 const float* __restrict__ disp_map,
                                                 unsigned short* __restrict__ p3,
                                                 float* __restrict__ disp) {
    int bid = blockIdx.x;               // over B*UVHW = 20000
    int b = bid / UVHW, j = bid % UVHW;
    int t = threadIdx.x;
    int h = t >> 5, lane = t & 31;      // 8 half-waves of 32 lanes, one head each

    __shared__ int linv[DD];
    __shared__ int minv2[DD];
    __shared__ int s_flag;
    __shared__ float sp[DD][H][UV];     // staged p for coalesced scatter

    if (t == 0) s_flag = 0;
    if (t < DD) {
        linv[t] = attn_inv[t * UVHW + j];
        minv2[t] = inv2[t * UVHW + j];
    }
    __syncthreads();
    // detect mask encoding: int32 (widened) has all bytes at offset%4!=0 == 0
    const unsigned char* mb = (const unsigned char*)maskbuf;
    if (t < 64) {
        if (mb[4 * t + 1] | mb[4 * t + 2] | mb[4 * t + 3]) s_flag = 1;
    }
    __syncthreads();
    bool isbyte = (s_flag != 0);
    const int* mw = (const int*)maskbuf;

    float vals[4];
    float m = -INFINITY;
#pragma unroll
    for (int kk = 0; kk < 4; ++kk) {
        int e = lane + kk * 32;
        float x = -INFINITY;
        if (e < MCOL) {
            int v = e / DD, d2 = e % DD;
            int l = linv[d2];
            float raw = aw2[((size_t)((size_t)b * L + l) * H + h) * UV + v];
            int mv = isbyte ? (int)mb[(size_t)j * MCOL + e] : mw[(size_t)j * MCOL + e];
            x = mv ? raw : -INFINITY;
        }
        vals[kk] = x;
        m = fmaxf(m, x);
    }
#pragma unroll
    for (int s = 16; s >= 1; s >>= 1) m = fmaxf(m, __shfl_xor(m, s, 32));
    float sum = 0.f;
#pragma unroll
    for (int kk = 0; kk < 4; ++kk) {
        float pe = expf(vals[kk] - m);  // -inf -> 0
        vals[kk] = pe;
        sum += pe;
    }
#pragma unroll
    for (int s = 16; s >= 1; s >>= 1) sum += __shfl_xor(sum, s, 32);
    float inv = 1.0f / sum;
    float dacc = 0.f;
#pragma unroll
    for (int kk = 0; kk < 4; ++kk) {
        int e = lane + kk * 32;
        if (e < MCOL) {
            float pe = vals[kk] * inv;
            int v = e / DD, d2 = e % DD;
            sp[d2][h][v] = pe;
            dacc += pe * disp_map[e];
        }
    }
#pragma unroll
    for (int s = 16; s >= 1; s >>= 1) dacc += __shfl_xor(dacc, s, 32);
    if (lane == 0) disp[((size_t)b * UVHW + j) * H + h] = dacc;
    __syncthreads();
    // scatter: 5 chunks of 512 contiguous bytes (one per d2 -> row m), bf16, zero-padded
    for (int e2 = t; e2 < DD * P3ROW; e2 += 256) {
        int d2 = e2 / P3ROW;
        int r = e2 % P3ROW;             // = h*32 + v
        int h2 = r >> 5, v2 = r & 31;
        float val = (v2 < UV) ? sp[d2][h2][v2] : 0.f;
        p3[((size_t)b * L + minv2[d2]) * P3ROW + r] = f2bf(val);
    }
}

// ---- Kernel 3: PV per (b,d,w,h); small LDS, broadcast/conflict-free reads,
//      register acc, coalesced atomics ----
__global__ __launch_bounds__(256) void k_pv(const float* __restrict__ qkv,
                                            const int* __restrict__ attn_idx,
                                            const unsigned short* __restrict__ p3,
                                            float* __restrict__ attn_out) {
    int bid = blockIdx.x;               // over B*DD*HW*H = 32000
    int b = bid / (DD * HW * H);
    int rem = bid % (DD * HW * H);
    int d = rem / (HW * H);
    int rem2 = rem % (HW * H);
    int w = rem2 / H, h = rem2 % H;
    int t = threadIdx.x;

    __shared__ int idxv[UV];
    __shared__ float vs[UV][HC + 1];
    __shared__ float aw7[UV][HC + 1];   // cols 0..24 used (p), rest pad

    if (t < UV) idxv[t] = attn_idx[(d * UV + t) * HW + w];
    __syncthreads();

    // V slice for this head: 25 rows x 128 B, float4
    if (t < UV * 8) {
        int u = t >> 3, c4 = t & 7;
        const float4* src = (const float4*)(qkv + ((size_t)(2 * B + b) * N + idxv[u]) * HHC + h * HC) + c4;
        float4 val = *src;
        vs[u][c4 * 4 + 0] = val.x; vs[u][c4 * 4 + 1] = val.y;
        vs[u][c4 * 4 + 2] = val.z; vs[u][c4 * 4 + 3] = val.w;
    }
    // p3 slice for this head: 25 rows x 64 B aligned, uint4 -> 8 bf16 each
    if (t >= 224 - 100 && t < 224) {    // use a different wave-range than V stage? keep simple: t<100 overlap is fine
    }
    if (t < UV * 4) {
        int u = t >> 2, q = t & 3;
        int m = (d * UV + u) * HW + w;
        uint4 pk = *((const uint4*)(p3 + ((size_t)b * L + m) * P3ROW + h * HC) + q);
        unsigned int wd[4] = {pk.x, pk.y, pk.z, pk.w};
        float* dst = &aw7[u][q * 8];
#pragma unroll
        for (int z = 0; z < 4; ++z) {
            dst[z * 2 + 0] = bf2f((unsigned short)(wd[z] & 0xffffu));
            dst[z * 2 + 1] = bf2f((unsigned short)(wd[z] >> 16));
        }
    }
    __syncthreads();

    // compute + coalesced atomics: e = u*32 + c
    for (int e = t; e < UV * HC; e += 256) {
        int u = e >> 5, c = e & 31;
        float acc = 0.f;
#pragma unroll
        for (int v = 0; v < UV; ++v)     // aw7 broadcast per half-wave; vs conflict-free
            acc += aw7[u][v] * vs[v][c];
        atomicAdd(attn_out + ((size_t)b * N + idxv[u]) * HHC + h * HC + c, acc);
    }
}

extern "C" void kernel_launch(void* const* d_in, const int* in_sizes, int n_in,
                              void* d_out, int out_size, void* d_ws, size_t ws_size,
                              hipStream_t stream) {
    const float* qkv      = (const float*)d_in[0];
    const float* disp_map = (const float*)d_in[1];
    const void*  mask     = d_in[2];
    const int*   attn_idx  = (const int*)d_in[3];
    const int*   attn_idx2 = (const int*)d_in[4];
    const int*   attn_inv  = (const int*)d_in[5];

    float* attn_out = (float*)d_out;                          // B*N*H*HC
    float* disp     = (float*)d_out + (size_t)B * N * H * HC; // B*UVHW*H

    float* aw2 = (float*)d_ws;                                     // B*L*H*UV floats (80 MB)
    unsigned short* p3 = (unsigned short*)(aw2 + (size_t)B * L * H * UV); // B*L*256 bf16 (51.2 MB)
    int* inv2 = (int*)(p3 + (size_t)B * L * P3ROW);                // L ints (0.2 MB)

    // attn_out is accumulated via atomics -> must be zeroed every call
    hipMemsetAsync(d_out, 0, (size_t)B * N * H * HC * sizeof(float), stream);

    k_inv<<<(L + 255) / 256, 256, 0, stream>>>(attn_idx2, inv2);
    k_qk<<<B * DD * HW, 256, 0, stream>>>(qkv, attn_idx, aw2);
    k_softmax<<<B * UVHW, 256, 0, stream>>>(aw2, attn_inv, inv2, mask, disp_map, p3, disp);
    k_pv<<<B * DD * HW * H, 256, 0, stream>>>(qkv, attn_idx, p3, attn_out);
}